// Round 1
// baseline (1374.600 us; speedup 1.0000x reference)
//
#include <hip/hip_runtime.h>
#include <hip/hip_bf16.h>
#include <stdint.h>

#define CIN  16
#define COUT 32
#define K2   9

// ---------- bf16 helpers (version-robust, RNE) ----------
__device__ __forceinline__ uint16_t f2bf(float f) {
    union { float f; uint32_t u; } a; a.f = f;
    uint32_t u = a.u;
    uint32_t r = u + 0x7FFFu + ((u >> 16) & 1u);   // round-to-nearest-even
    return (uint16_t)(r >> 16);
}
__device__ __forceinline__ float bf2f(uint32_t bits16) {
    union { uint32_t u; float f; } a; a.u = bits16 << 16; return a.f;
}

// ---------- mask-width detection ----------
// nbr_mask row k=4 (center) is all-true. If the buffer is int32, words
// [4n, 4n+64) are all exactly 1. If it is 1-byte bools, those words land in
// the k=7/8 byte region (random 0/1 bytes) and the probability all 64 words
// equal 1 is ~0. flag=1 -> int32 mask, flag=0 -> byte mask.
__global__ void detect_mask_kernel(const uint32_t* __restrict__ mw,
                                   int* __restrict__ flag, int n) {
    int t = threadIdx.x;
    uint32_t w = mw[(size_t)4 * (size_t)n + (size_t)t];
    unsigned long long b = __ballot(w == 1u);
    if (t == 0) *flag = (b == ~0ull) ? 1 : 0;
}

// ---------- conv1 + relu -> h ----------
template <int HBF>
__global__ void __launch_bounds__(256)
conv1_kernel(const float* __restrict__ x,
             const float* __restrict__ W1,
             const float* __restrict__ b1,
             const int*   __restrict__ nidx,
             const void*  __restrict__ nmask,
             const int*   __restrict__ mflag,
             void*        __restrict__ hbuf,
             int n)
{
    const int i = blockIdx.x * blockDim.x + threadIdx.x;
    if (i >= n) return;
    const int mode32 = *mflag;                 // wave-uniform scalar load
    const int*     m32 = (const int*)nmask;
    const uint8_t* m8  = (const uint8_t*)nmask;

    float acc[COUT];
    #pragma unroll
    for (int o = 0; o < COUT; ++o) acc[o] = b1[o];

    for (int k = 0; k < K2; ++k) {
        const size_t e = (size_t)k * (size_t)n + (size_t)i;
        const int id = nidx[e];
        const bool mv = mode32 ? (m32[e] != 0) : (m8[e] != 0);
        if (mv) {
            const float4* xr = (const float4*)(x + (size_t)id * CIN);
            float xv[CIN];
            #pragma unroll
            for (int q = 0; q < 4; ++q) {
                float4 a = xr[q];
                xv[4*q+0] = a.x; xv[4*q+1] = a.y; xv[4*q+2] = a.z; xv[4*q+3] = a.w;
            }
            const float* Wk = W1 + k * (CIN * COUT);
            #pragma unroll
            for (int c = 0; c < CIN; ++c) {
                const float xc = xv[c];
                #pragma unroll
                for (int o = 0; o < COUT; ++o)
                    acc[o] = fmaf(xc, Wk[c * COUT + o], acc[o]);
            }
        }
    }

    #pragma unroll
    for (int o = 0; o < COUT; ++o) acc[o] = fmaxf(acc[o], 0.0f);

    if (HBF) {
        uint16_t* hp = (uint16_t*)hbuf + (size_t)i * COUT;
        uint4* hq = (uint4*)hp;
        #pragma unroll
        for (int j = 0; j < 4; ++j) {
            uint4 w;
            w.x = (uint32_t)f2bf(acc[8*j+0]) | ((uint32_t)f2bf(acc[8*j+1]) << 16);
            w.y = (uint32_t)f2bf(acc[8*j+2]) | ((uint32_t)f2bf(acc[8*j+3]) << 16);
            w.z = (uint32_t)f2bf(acc[8*j+4]) | ((uint32_t)f2bf(acc[8*j+5]) << 16);
            w.w = (uint32_t)f2bf(acc[8*j+6]) | ((uint32_t)f2bf(acc[8*j+7]) << 16);
            hq[j] = w;
        }
    } else {
        float4* hq = (float4*)((float*)hbuf + (size_t)i * COUT);
        #pragma unroll
        for (int j = 0; j < 8; ++j)
            hq[j] = make_float4(acc[4*j+0], acc[4*j+1], acc[4*j+2], acc[4*j+3]);
    }
}

// ---------- conv2 + residual proj + relu -> out ----------
template <int HBF>
__global__ void __launch_bounds__(256)
conv2_kernel(const float* __restrict__ x,
             const float* __restrict__ W2,
             const float* __restrict__ b2,
             const float* __restrict__ Wp,
             const float* __restrict__ bp,
             const int*   __restrict__ nidx,
             const void*  __restrict__ nmask,
             const int*   __restrict__ mflag,
             const void*  __restrict__ hbuf,
             float*       __restrict__ out,
             int n)
{
    const int i = blockIdx.x * blockDim.x + threadIdx.x;
    if (i >= n) return;
    const int mode32 = *mflag;
    const int*     m32 = (const int*)nmask;
    const uint8_t* m8  = (const uint8_t*)nmask;

    float acc[COUT];
    #pragma unroll
    for (int o = 0; o < COUT; ++o) acc[o] = b2[o] + bp[o];

    // residual 1x1 projection: x[i] @ Wp
    {
        const float4* xr = (const float4*)(x + (size_t)i * CIN);
        float xv[CIN];
        #pragma unroll
        for (int q = 0; q < 4; ++q) {
            float4 a = xr[q];
            xv[4*q+0] = a.x; xv[4*q+1] = a.y; xv[4*q+2] = a.z; xv[4*q+3] = a.w;
        }
        #pragma unroll
        for (int c = 0; c < CIN; ++c) {
            const float xc = xv[c];
            #pragma unroll
            for (int o = 0; o < COUT; ++o)
                acc[o] = fmaf(xc, Wp[c * COUT + o], acc[o]);
        }
    }

    for (int k = 0; k < K2; ++k) {
        const size_t e = (size_t)k * (size_t)n + (size_t)i;
        const int id = nidx[e];
        const bool mv = mode32 ? (m32[e] != 0) : (m8[e] != 0);
        if (mv) {
            float hv[COUT];
            if (HBF) {
                const uint4* hr = (const uint4*)((const uint16_t*)hbuf + (size_t)id * COUT);
                #pragma unroll
                for (int j = 0; j < 4; ++j) {
                    uint4 w = hr[j];
                    hv[8*j+0] = bf2f(w.x & 0xFFFFu); hv[8*j+1] = bf2f(w.x >> 16);
                    hv[8*j+2] = bf2f(w.y & 0xFFFFu); hv[8*j+3] = bf2f(w.y >> 16);
                    hv[8*j+4] = bf2f(w.z & 0xFFFFu); hv[8*j+5] = bf2f(w.z >> 16);
                    hv[8*j+6] = bf2f(w.w & 0xFFFFu); hv[8*j+7] = bf2f(w.w >> 16);
                }
            } else {
                const float4* hr = (const float4*)((const float*)hbuf + (size_t)id * COUT);
                #pragma unroll
                for (int j = 0; j < 8; ++j) {
                    float4 a = hr[j];
                    hv[4*j+0] = a.x; hv[4*j+1] = a.y; hv[4*j+2] = a.z; hv[4*j+3] = a.w;
                }
            }
            const float* Wk = W2 + k * (COUT * COUT);
            #pragma unroll
            for (int c = 0; c < COUT; ++c) {
                const float hc = hv[c];
                #pragma unroll
                for (int o = 0; o < COUT; ++o)
                    acc[o] = fmaf(hc, Wk[c * COUT + o], acc[o]);
            }
        }
    }

    float4* oq = (float4*)(out + (size_t)i * COUT);
    #pragma unroll
    for (int j = 0; j < 8; ++j)
        oq[j] = make_float4(fmaxf(acc[4*j+0], 0.0f), fmaxf(acc[4*j+1], 0.0f),
                            fmaxf(acc[4*j+2], 0.0f), fmaxf(acc[4*j+3], 0.0f));
}

extern "C" void kernel_launch(void* const* d_in, const int* in_sizes, int n_in,
                              void* d_out, int out_size, void* d_ws, size_t ws_size,
                              hipStream_t stream) {
    const float* x    = (const float*)d_in[0];
    const float* W1   = (const float*)d_in[1];
    const float* b1   = (const float*)d_in[2];
    const float* W2   = (const float*)d_in[3];
    const float* b2   = (const float*)d_in[4];
    const float* Wp   = (const float*)d_in[5];
    const float* bp   = (const float*)d_in[6];
    const int*   nidx = (const int*)d_in[7];
    const void*  nmask = d_in[8];
    const int n = in_sizes[0] / CIN;

    int*  mflag = (int*)d_ws;                    // first 256 B reserved for flag
    void* hbuf  = (void*)((char*)d_ws + 256);

    const size_t need_f32 = 256 + (size_t)n * COUT * sizeof(float);
    const bool hbf = (ws_size < need_f32);       // bf16-h fallback if ws too small

    detect_mask_kernel<<<1, 64, 0, stream>>>((const uint32_t*)nmask, mflag, n);

    const int block = 256;
    const int grid  = (n + block - 1) / block;
    if (!hbf) {
        conv1_kernel<0><<<grid, block, 0, stream>>>(x, W1, b1, nidx, nmask, mflag, hbuf, n);
        conv2_kernel<0><<<grid, block, 0, stream>>>(x, W2, b2, Wp, bp, nidx, nmask, mflag, hbuf, (float*)d_out, n);
    } else {
        conv1_kernel<1><<<grid, block, 0, stream>>>(x, W1, b1, nidx, nmask, mflag, hbuf, n);
        conv2_kernel<1><<<grid, block, 0, stream>>>(x, W2, b2, Wp, bp, nidx, nmask, mflag, hbuf, (float*)d_out, n);
    }
}